// Round 7
// baseline (197.091 us; speedup 1.0000x reference)
//
#include <hip/hip_runtime.h>

#define T_DIM 8192
#define D_DIM 256
#define N_DIM 64
#define LOG2E 1.44269504f

typedef __bf16 bf16x8 __attribute__((ext_vector_type(8)));
typedef __bf16 bf16x4 __attribute__((ext_vector_type(4)));
typedef float f32x16 __attribute__((ext_vector_type(16)));

__device__ __forceinline__ f32x16 zero16() {
  f32x16 v;
#pragma unroll
  for (int i = 0; i < 16; ++i) v[i] = 0.f;
  return v;
}

// DHf: fragment-major. Row-group G=t>>5, chunk c=kk*2+h, lane l31:
// DHf[G*2048 + c*256 + l31*8 .. +7] = DH[n=c*8+e][t=G*32+l31].

// ---------------------------------------------------------------------------
// K1: DHf (bf16, fragment-major) via split-bf16 MFMA, lbe[t]=lb*log2e,
//     rowsum[t]=0. grid 128 x 256.  (R4-proven, byte-identical)
// ---------------------------------------------------------------------------
__global__ __launch_bounds__(256) void k_dh(const float* __restrict__ H,
                                            const float* __restrict__ Dm,
                                            __bf16* __restrict__ DHf,
                                            float* __restrict__ lbe,
                                            float* __restrict__ rowsum) {
  __shared__ __bf16 HlThi[64 * 264];
  __shared__ __bf16 HlTlo[64 * 264];
  __shared__ __bf16 DHs[64 * 72];
  const int tid = threadIdx.x;
  const int t0 = blockIdx.x * 64;
  const int lane = tid & 63;
  const int wave = tid >> 6;
  const int h = lane >> 5;
  const int l31 = lane & 31;
  const float4* H4 = (const float4*)H;
#pragma unroll
  for (int r = 0; r < 16; ++r) {
    int idx = r * 256 + tid;
    int d = idx >> 4, tc = idx & 15;
    float4 v = H4[(size_t)d * (T_DIM / 4) + (t0 >> 2) + tc];
    float vv[4] = {v.x, v.y, v.z, v.w};
#pragma unroll
    for (int i = 0; i < 4; ++i) {
      __bf16 hi = (__bf16)vv[i];
      float lo = vv[i] - (float)hi;
      HlThi[(tc * 4 + i) * 264 + d] = hi;
      HlTlo[(tc * 4 + i) * 264 + d] = (__bf16)lo;
    }
  }
  __syncthreads();
  const int tt = wave & 1, nh = wave >> 1;
  const int m = tt * 32 + l31;
  const int n = nh * 32 + l31;
  f32x16 c = zero16();
  for (int kk = 0; kk < 16; ++kk) {
    bf16x8 ahi = *(const bf16x8*)&HlThi[m * 264 + kk * 16 + h * 8];
    bf16x8 alo = *(const bf16x8*)&HlTlo[m * 264 + kk * 16 + h * 8];
    const float4* dp = (const float4*)(Dm + (size_t)n * 256 + kk * 16 + h * 8);
    float4 b0 = dp[0], b1 = dp[1];
    float bv[8] = {b0.x, b0.y, b0.z, b0.w, b1.x, b1.y, b1.z, b1.w};
    bf16x8 bhi, blo;
#pragma unroll
    for (int i = 0; i < 8; ++i) {
      __bf16 hi = (__bf16)bv[i];
      bhi[i] = hi;
      blo[i] = (__bf16)(bv[i] - (float)hi);
    }
    c = __builtin_amdgcn_mfma_f32_32x32x16_bf16(ahi, bhi, c, 0, 0, 0);
    c = __builtin_amdgcn_mfma_f32_32x32x16_bf16(ahi, blo, c, 0, 0, 0);
    c = __builtin_amdgcn_mfma_f32_32x32x16_bf16(alo, bhi, c, 0, 0, 0);
  }
#pragma unroll
  for (int r = 0; r < 16; ++r) {
    int row = tt * 32 + (r & 3) + 8 * (r >> 2) + 4 * h;
    DHs[row * 72 + n] = (__bf16)c[r];
  }
  __syncthreads();
#pragma unroll
  for (int r = 0; r < 2; ++r) {
    int idx = r * 256 + tid;
    int g = idx >> 8, cc = (idx >> 5) & 7, l = idx & 31;
    bf16x8 w = *(const bf16x8*)&DHs[(g * 32 + l) * 72 + cc * 8];
    *(bf16x8*)(DHf + (size_t)(blockIdx.x * 2 + g) * 2048 + cc * 256 + l * 8) = w;
  }
  if (tid < 64) {
    float s = 0.f;
#pragma unroll
    for (int q = 0; q < 8; ++q) {
      bf16x8 w = *(const bf16x8*)&DHs[tid * 72 + q * 8];
#pragma unroll
      for (int i = 0; i < 8; ++i) { float f = (float)w[i]; s += f * f; }
    }
    lbe[t0 + tid] = -0.5f * s * LOG2E;
    rowsum[t0 + tid] = 0.f;
  }
}

// ---------------------------------------------------------------------------
// K2: rowsum[t] += sum_j exp(S+lb). grid 512 x 512 (R3-proven body)
//     + FINISHER fusion of scaleH: the 16th j-split block to finish a
//     t-tile (256 t's) computes rinv and writes that tile's scaled,
//     pre-swizzled Hbf_sw stripe. Counter handshake = R5-proven fence
//     pattern; no spin-waits (deadlock-free).
// ---------------------------------------------------------------------------
__global__ __launch_bounds__(512, 4) void k_rowsum(const __bf16* __restrict__ DHf,
                                                   const float* __restrict__ lbe,
                                                   float* __restrict__ rowsum,
                                                   const float* __restrict__ H,
                                                   __bf16* __restrict__ Hbf_sw,
                                                   unsigned int* __restrict__ cnt) {
  __shared__ float red2[256][33];
  __shared__ float rinvL[256];
  __shared__ int isLast;
  const int tid = threadIdx.x;
  const int lane = tid & 63;
  const int wave = tid >> 6;
  const int h = lane >> 5;
  const int l31 = lane & 31;
  const int t0 = (int)(blockIdx.x >> 4) * 256;
  const int jbase = (int)(blockIdx.x & 15) * 512;
  const size_t Gt = (size_t)(t0 >> 5) + wave;
  bf16x8 aR[4];
#pragma unroll
  for (int kk = 0; kk < 4; ++kk)
    aR[kk] = *(const bf16x8*)(DHf + Gt * 2048 + kk * 512 + lane * 8);
  float racc[16];
#pragma unroll
  for (int r = 0; r < 16; ++r) racc[r] = 0.f;
  bf16x8 b[4];
  {
    const size_t Gj = (size_t)(jbase >> 5);
#pragma unroll
    for (int kk = 0; kk < 4; ++kk)
      b[kk] = *(const bf16x8*)(DHf + Gj * 2048 + kk * 512 + lane * 8);
  }
  for (int jit = 0; jit < 16; ++jit) {
    bf16x8 bn[4];
    if (jit < 15) {
      const size_t Gj = (size_t)(jbase >> 5) + jit + 1;
#pragma unroll
      for (int kk = 0; kk < 4; ++kk)
        bn[kk] = *(const bf16x8*)(DHf + Gj * 2048 + kk * 512 + lane * 8);
    }
    const float lbv = lbe[jbase + jit * 32 + l31];
    f32x16 s = zero16();
    s = __builtin_amdgcn_mfma_f32_32x32x16_bf16(aR[0], b[0], s, 0, 0, 0);
    s = __builtin_amdgcn_mfma_f32_32x32x16_bf16(aR[1], b[1], s, 0, 0, 0);
    s = __builtin_amdgcn_mfma_f32_32x32x16_bf16(aR[2], b[2], s, 0, 0, 0);
    s = __builtin_amdgcn_mfma_f32_32x32x16_bf16(aR[3], b[3], s, 0, 0, 0);
#pragma unroll
    for (int r = 0; r < 16; ++r)
      racc[r] += __builtin_amdgcn_exp2f(__builtin_fmaf(s[r], LOG2E, lbv));
    if (jit < 15) {
#pragma unroll
      for (int kk = 0; kk < 4; ++kk) b[kk] = bn[kk];
    }
  }
#pragma unroll
  for (int r = 0; r < 16; ++r) {
    int tl = wave * 32 + (r & 3) + 8 * (r >> 2) + 4 * h;
    red2[tl][l31] = racc[r];
  }
  __syncthreads();
  if (tid < 256) {
    float s = 0.f;
#pragma unroll 8
    for (int c = 0; c < 32; ++c) s += red2[tid][c];
    atomicAdd(&rowsum[t0 + tid], s);
  }
  // ---- finisher handshake ----
  __syncthreads();
  if (tid == 0) {
    __threadfence();  // release: our atomicAdds ordered before counter bump
    unsigned int old = atomicAdd(&cnt[blockIdx.x >> 4], 1u);
    isLast = (old == 15u) ? 1 : 0;
  }
  __syncthreads();
  if (isLast) {
    if (tid == 0) __threadfence();  // acquire: invalidate stale lines
    __syncthreads();
    if (tid < 256)
      rinvL[tid] = 1.0f / __hip_atomic_load(&rowsum[t0 + tid], __ATOMIC_RELAXED,
                                            __HIP_MEMORY_SCOPE_AGENT);
    __syncthreads();
    const int tb0 = t0 >> 6;  // first t64-block of this tile (4 of them)
#pragma unroll
    for (int pass = 0; pass < 16; ++pass) {
      int gidx = pass * 512 + tid;        // 8192 bf16x8 groups
      int tbl = gidx >> 11;               // 0..3 local t64-block
      int rem = gidx & 2047;
      int d = rem >> 3, tbp = rem & 7;
      int swz = (d ^ (d >> 3)) & 7;
      int tloc = (tbp ^ swz) << 3;
      const float4* hp =
          (const float4*)(H + (size_t)d * T_DIM + (tb0 + tbl) * 64 + tloc);
      float4 v0 = hp[0], v1 = hp[1];
      const float* rl = &rinvL[tbl * 64 + tloc];
      float4 r0 = *(const float4*)rl;
      float4 r1 = *(const float4*)(rl + 4);
      bf16x8 w;
      w[0] = (__bf16)(v0.x * r0.x); w[1] = (__bf16)(v0.y * r0.y);
      w[2] = (__bf16)(v0.z * r0.z); w[3] = (__bf16)(v0.w * r0.w);
      w[4] = (__bf16)(v1.x * r1.x); w[5] = (__bf16)(v1.y * r1.y);
      w[6] = (__bf16)(v1.z * r1.z); w[7] = (__bf16)(v1.w * r1.w);
      *(bf16x8*)(Hbf_sw + (size_t)(tb0 + tbl) * 16384 + (size_t)d * 64 +
                 tbp * 8) = w;
    }
  }
}

// ---------------------------------------------------------------------------
// K3: Zp[ts][d][j] = sum_{t in slice} H'[d][t] * E[t][j].
//     R4-proven pipeline (61.4us): dbuf Hs/Pt, aR/aRn dbuf, setprio,
//     plane stores. + FINISHER fusion of zred: 4th block of each
//     (dh,j0) group reads the 4 planes and writes Z = l2*sum.
//     grid 512 = 64 j-tiles(128) x 2 d-halves x 4 t-splits; 2 blk/CU.
// ---------------------------------------------------------------------------
__global__ __launch_bounds__(256, 2) void k_z(const __bf16* __restrict__ Hbf_sw,
                                              const __bf16* __restrict__ DHf,
                                              const float* __restrict__ lbe,
                                              const float* __restrict__ l2p,
                                              float* __restrict__ Zp,
                                              float* __restrict__ Z,
                                              unsigned int* __restrict__ cnt2) {
  __shared__ __bf16 Hs[2][128 * 64];  // [dl][t] swizzled, 2 x 16 KB
  __shared__ __bf16 Pt[2][128 * 64];  // [j][t] swizzled,  2 x 16 KB
  const int tid = threadIdx.x;
  const int lane = tid & 63;
  const int wave = tid >> 6;
  const int h = lane >> 5;
  const int l31 = lane & 31;
  const int bx = blockIdx.x;
  const int ts = bx & 3;
  const int dh = (bx >> 2) & 1;
  const int j0 = (bx >> 3) * 128;
  const int s_tt = wave & 1, s_jg = wave >> 1;
  bf16x8 bS[2][4];
  float lbv[2];
#pragma unroll
  for (int q = 0; q < 2; ++q) {
    const size_t Gj = (j0 >> 5) + s_jg * 2 + q;
#pragma unroll
    for (int kk = 0; kk < 4; ++kk)
      bS[q][kk] = *(const bf16x8*)(DHf + Gj * 2048 + kk * 512 + lane * 8);
    lbv[q] = lbe[j0 + (s_jg * 2 + q) * 32 + l31];
  }
  f32x16 acc[2][2];
#pragma unroll
  for (int u = 0; u < 2; ++u)
#pragma unroll
    for (int v = 0; v < 2; ++v) acc[u][v] = zero16();

#define DMA_HS(buf_, it_)                                                       \
  {                                                                             \
    const __bf16* gsrc =                                                        \
        Hbf_sw + (size_t)(ts * 32 + (it_)) * 16384 + (size_t)dh * 8192;         \
    _Pragma("unroll") for (int r = 0; r < 4; ++r) {                             \
      int chunk = wave * 4 + r;                                                 \
      __builtin_amdgcn_global_load_lds(                                         \
          (const __attribute__((address_space(1))) unsigned int*)(gsrc +        \
              chunk * 512 + lane * 8),                                          \
          (__attribute__((address_space(3))) unsigned int*)(&Hs[buf_][0] +      \
              chunk * 512),                                                     \
          16, 0, 0);                                                            \
    }                                                                           \
  }

#define LOAD_AR(reg_, n_)                                                       \
  {                                                                             \
    const size_t Gt_ = (size_t)(ts * 64 + (n_)*2 + s_tt);                       \
    _Pragma("unroll") for (int kk = 0; kk < 4; ++kk)                            \
        (reg_)[kk] = *(const bf16x8*)(DHf + Gt_ * 2048 + kk * 512 + lane * 8);  \
  }

#define S_PHASE(p_, reg_)                                                       \
  {                                                                             \
    _Pragma("unroll") for (int q = 0; q < 2; ++q) {                             \
      f32x16 s = zero16();                                                      \
      _Pragma("unroll") for (int kk = 0; kk < 4; ++kk)                          \
          s = __builtin_amdgcn_mfma_f32_32x32x16_bf16((reg_)[kk], bS[q][kk], s, \
                                                      0, 0, 0);                 \
      const int jl = (s_jg * 2 + q) * 32 + l31;                                 \
      const int sj = (jl ^ (jl >> 3)) & 7;                                      \
      _Pragma("unroll") for (int g = 0; g < 4; ++g) {                           \
        const int tl = s_tt * 32 + g * 8 + 4 * h;                               \
        bf16x4 pv;                                                              \
        pv[0] = (__bf16)__builtin_amdgcn_exp2f(                                 \
            __builtin_fmaf(s[g * 4 + 0], LOG2E, lbv[q]));                       \
        pv[1] = (__bf16)__builtin_amdgcn_exp2f(                                 \
            __builtin_fmaf(s[g * 4 + 1], LOG2E, lbv[q]));                       \
        pv[2] = (__bf16)__builtin_amdgcn_exp2f(                                 \
            __builtin_fmaf(s[g * 4 + 2], LOG2E, lbv[q]));                       \
        pv[3] = (__bf16)__builtin_amdgcn_exp2f(                                 \
            __builtin_fmaf(s[g * 4 + 3], LOG2E, lbv[q]));                       \
        const int cchunk = tl >> 3;                                             \
        *(bf16x4*)&Pt[p_][jl * 64 + ((cchunk ^ sj) << 3) + 4 * h] = pv;         \
      }                                                                         \
    }                                                                           \
  }

#define Z_PHASE(p_)                                                             \
  {                                                                             \
    __builtin_amdgcn_s_setprio(1);                                              \
    _Pragma("unroll") for (int kk = 0; kk < 4; ++kk) {                          \
      const int c = kk * 2 + h;                                                 \
      bf16x8 af[2], bw[2];                                                      \
      _Pragma("unroll") for (int u = 0; u < 2; ++u) {                           \
        int dl = (wave & 1) * 64 + u * 32 + l31;                                \
        af[u] =                                                                 \
            *(const bf16x8*)&Hs[p_][dl * 64 + ((c ^ ((dl ^ (dl >> 3)) & 7)) << 3)]; \
      }                                                                         \
      _Pragma("unroll") for (int v = 0; v < 2; ++v) {                           \
        int j = (wave >> 1) * 64 + v * 32 + l31;                                \
        bw[v] =                                                                 \
            *(const bf16x8*)&Pt[p_][j * 64 + ((c ^ ((j ^ (j >> 3)) & 7)) << 3)]; \
      }                                                                         \
      _Pragma("unroll") for (int u = 0; u < 2; ++u)                             \
          _Pragma("unroll") for (int v = 0; v < 2; ++v)                         \
              acc[u][v] = __builtin_amdgcn_mfma_f32_32x32x16_bf16(              \
                  af[u], bw[v], acc[u][v], 0, 0, 0);                            \
    }                                                                           \
    __builtin_amdgcn_s_setprio(0);                                              \
  }

  bf16x8 aR[4], aRn[4];
  LOAD_AR(aR, 0);
  DMA_HS(0, 0);
  S_PHASE(0, aR);
  LOAD_AR(aRn, 1);
  __syncthreads();

  for (int ii = 0; ii < 16; ++ii) {
    const int it0 = ii * 2;
    DMA_HS(1, it0 + 1);
    if (it0 < 30) LOAD_AR(aR, it0 + 2);
    S_PHASE(1, aRn);
    Z_PHASE(0);
    __syncthreads();
    if (it0 + 1 < 31) {
      DMA_HS(0, it0 + 2);
      S_PHASE(0, aR);
    }
    if (it0 + 1 < 30) LOAD_AR(aRn, it0 + 3);
    Z_PHASE(1);
    __syncthreads();
  }
#undef Z_PHASE
#undef S_PHASE
#undef LOAD_AR
#undef DMA_HS
  // ---- epilogue: plane stores ----
  float* zp = Zp + (size_t)ts * (256 * (size_t)T_DIM);
#pragma unroll
  for (int u = 0; u < 2; ++u)
#pragma unroll
    for (int v = 0; v < 2; ++v)
#pragma unroll
      for (int r = 0; r < 16; ++r) {
        int d = dh * 128 + (wave & 1) * 64 + u * 32 + (r & 3) + 8 * (r >> 2) + 4 * h;
        int j = j0 + (wave >> 1) * 64 + v * 32 + l31;
        zp[(size_t)d * T_DIM + j] = acc[u][v][r];
      }
  // ---- finisher: 4th block of (dh,j0) group reduces planes into Z ----
  __syncthreads();
  int* flagp = (int*)&Hs[0][0];  // LDS reuse (dead after main loop)
  if (tid == 0) {
    __threadfence();  // release: plane stores flushed before bump
    unsigned int old = atomicAdd(&cnt2[bx >> 2], 1u);
    *flagp = (old == 3u) ? 1 : 0;
  }
  __syncthreads();
  if (*flagp) {
    if (tid == 0) __threadfence();  // acquire: invalidate stale lines
    __syncthreads();
    const float l2v = l2p[0];
    const float4* zp4 = (const float4*)Zp;
    float4* Z4 = (float4*)Z;
    const int jq = (j0 >> 2) + (tid & 31);
#pragma unroll
    for (int pass = 0; pass < 16; ++pass) {
      int d = dh * 128 + pass * 8 + (tid >> 5);
      size_t rowq = (size_t)d * (T_DIM / 4) + jq;
      float4 a = zp4[rowq];
#pragma unroll
      for (int s = 1; s < 4; ++s) {
        float4 b = zp4[(size_t)s * 524288 + rowq];
        a.x += b.x; a.y += b.y; a.z += b.z; a.w += b.w;
      }
      float4 o = {a.x * l2v, a.y * l2v, a.z * l2v, a.w * l2v};
      Z4[rowq] = o;
    }
  }
}

// ---------------------------------------------------------------------------
extern "C" void kernel_launch(void* const* d_in, const int* in_sizes, int n_in,
                              void* d_out, int out_size, void* d_ws,
                              size_t ws_size, hipStream_t stream) {
  (void)in_sizes; (void)n_in; (void)out_size; (void)ws_size;
  const float* H = (const float*)d_in[0];
  const float* Dm = (const float*)d_in[1];
  const float* l2 = (const float*)d_in[2];
  float* Z = (float*)d_out;
  char* ws = (char*)d_ws;
  __bf16* DHf = (__bf16*)ws;                          // 1,048,576 B
  float* lbe = (float*)(ws + 1048576);                // 32,768 B
  float* rowsum = (float*)(ws + 1081344);             // 32,768 B
  unsigned int* cnt = (unsigned int*)(ws + 1114112);  // 128 B (32 t-tiles)
  unsigned int* cnt2 = (unsigned int*)(ws + 1114240); // 512 B (128 groups)
  __bf16* Hbf_sw = (__bf16*)(ws + 1118208);           // 4,194,304 B
  float* Zp = (float*)(ws + 5312512);                 // 33,554,432 B (4 planes)

  hipMemsetAsync(ws + 1114112, 0, 1024, stream);
  k_dh<<<128, 256, 0, stream>>>(H, Dm, DHf, lbe, rowsum);
  k_rowsum<<<512, 512, 0, stream>>>(DHf, lbe, rowsum, H, Hbf_sw, cnt);
  k_z<<<512, 256, 0, stream>>>(Hbf_sw, DHf, lbe, l2, Zp, Z, cnt2);
}